// Round 2
// baseline (194.293 us; speedup 1.0000x reference)
//
#include <hip/hip_runtime.h>
#include <math.h>

typedef __attribute__((ext_vector_type(8))) short s8v;   // 8 x bf16 (4 VGPRs) — MFMA A/B frag
typedef __attribute__((ext_vector_type(4))) float f4v;   // 4 x fp32 — MFMA C/D frag
typedef unsigned short u16;
typedef unsigned int u32;

constexpr int Bsz = 4, NQ = 4096, NC = 1024, NH = 8, DH = 64, DI = 512, DC = 768;

__device__ __forceinline__ u16 f2bf(float f) {
  union { float f; u32 u; } v; v.f = f;
  u32 r = v.u + 0x7fff + ((v.u >> 16) & 1);  // RNE
  return (u16)(r >> 16);
}

// pack two f32 -> two bf16 in one dword (round-half-up) — used in V epilogue
__device__ __forceinline__ u32 pack2(float a, float b) {
  union { float f; u32 u; } ua, ub; ua.f = a; ub.f = b;
#if __has_builtin(__builtin_amdgcn_perm)
  return __builtin_amdgcn_perm(ub.u + 0x8000u, ua.u + 0x8000u, 0x07060302u);
#else
  return ((ub.u + 0x8000u) & 0xffff0000u) | ((ua.u + 0x8000u) >> 16);
#endif
}

// single-instruction RNE pack (v_cvt_pk_bf16_f32): lo16=bf16(a), hi16=bf16(b)
__device__ __forceinline__ u32 cvtpk(float a, float b) {
  u32 r;
  asm("v_cvt_pk_bf16_f32 %0, %1, %2" : "=v"(r) : "v"(a), "v"(b));
  return r;
}

#if __has_builtin(__builtin_amdgcn_exp2f)
#define EXP2(x) __builtin_amdgcn_exp2f(x)
#else
#define EXP2(x) exp2f(x)
#endif

// async global->LDS, 16B per lane (m97 pattern)
__device__ __forceinline__ void g2l16(const void* g, void* l) {
  __builtin_amdgcn_global_load_lds((const __attribute__((address_space(1))) u32*)g,
                                   (__attribute__((address_space(3))) u32*)l, 16, 0, 0);
}

// ---------------- prep: weight transposes only (x/ctx cast fused into proj_all) --------
__global__ __launch_bounds__(256) void prep(const float* __restrict__ Wq, const float* __restrict__ Wk,
                                            const float* __restrict__ Wv, const float* __restrict__ Wo,
                                            u16* __restrict__ wqT, u16* __restrict__ wkvT,
                                            u16* __restrict__ woT) {
  int idx = blockIdx.x;                   // [0,384)
  int z = idx / 96, rem = idx % 96, kx = rem % 12, ny = rem / 12;
  const float* src; u16* dst; int K; const int N = 512;
  if (z == 0)      { src = Wq; dst = wqT;              K = 512; }
  else if (z == 1) { src = Wk; dst = wkvT;             K = 768; }
  else if (z == 2) { src = Wv; dst = wkvT + 512 * 768; K = 768; }
  else             { src = Wo; dst = woT;              K = 512; }
  int k0 = kx * 64, n0 = ny * 64;
  if (k0 >= K) return;
  __shared__ u16 t[64][65];
  int tid = threadIdx.x, jr = tid & 63, ir = tid >> 6;
  for (int it = 0; it < 16; ++it) { int i = it * 4 + ir; t[i][jr] = f2bf(src[(size_t)(k0 + i) * N + n0 + jr]); }
  __syncthreads();
  for (int it = 0; it < 16; ++it) { int i = it * 4 + ir; dst[(size_t)(n0 + i) * K + k0 + jr] = t[jr][i]; }
}

// ---------------- shared GEMM body: 128x128 tile, BK=32, dbuf staging ----------------
// LDS tiles [128][32] bf16; rows are 4 chunks of 8 elems (16B). XOR-chunk swizzle
// chunk' = chunk ^ ((row>>1)&3): stored content at linear position p holds global chunk
// p ^ sw(row) (pre-swizzled SOURCE, linear g2l16/ds_write dest — rule #21 involution).
// Read side: chunk = quad ^ ((l16>>1)&3) — a per-thread constant. Kills the 4-way
// ds_read_b128 bank conflict (1.8M conflict-cycles in R1 profile).
// F32A=true: A is fp32 in global; reg-stage (float4 loads) + cvt_pk + ds_write_b128,
// T14-split: loads issued right after barrier, ds_write after the MFMA cluster.
// MODE 0: bf16 C, scaled. MODE 1: fp32 C + bias. MODE 2: KV fused (K cols -> Kb,
// V cols -> Vt transposed + key-permuted).
template <int MODE, bool F32A>
__device__ __forceinline__ void gemm_body(const void* __restrict__ Av, const u16* __restrict__ Bt,
                                          void* __restrict__ C0, void* __restrict__ C1,
                                          const float* __restrict__ bias, int N, int K,
                                          float oscale, int nbx, int mby,
                                          u16* Al, u16* Bl) {   // Al/Bl: [2][128][32]
  int mb = mby * 128, nb = nbx * 128;
  int tid = threadIdx.x, lane = tid & 63, quad = lane >> 4, l16 = lane & 15, wave = tid >> 6;
  int wm = (wave >> 1) * 64, wn = (wave & 1) * 64;
  f4v acc[4][4];
  #pragma unroll
  for (int i = 0; i < 4; i++)
    #pragma unroll
    for (int j = 0; j < 4; j++) acc[i][j] = (f4v){0.f, 0.f, 0.f, 0.f};

  int r0 = tid >> 2;
  int cs = ((tid & 3) ^ ((r0 >> 1) & 3)) * 8;     // swizzled source chunk -> element offset
  int lin = tid * 8;                               // linear LDS dest (elements)
  const u16* Bp0 = Bt + (size_t)(nb + r0) * K + cs;
  const u16* Bp1 = Bt + (size_t)(nb + r0 + 64) * K + cs;
  const float* Af0 = nullptr; const float* Af1 = nullptr;
  const u16* Ap0 = nullptr; const u16* Ap1 = nullptr;
  if constexpr (F32A) {
    Af0 = (const float*)Av + (size_t)(mb + r0) * K + cs;
    Af1 = Af0 + (size_t)64 * K;
  } else {
    Ap0 = (const u16*)Av + (size_t)(mb + r0) * K + cs;
    Ap1 = Ap0 + (size_t)64 * K;
  }
  float4 a00, a01, a10, a11;                       // in-flight fp32 A (T14 split)

#define BSTAGE(k0, buf) do { u16* bl_ = Bl + (buf) * 4096; \
    g2l16(Bp0 + (k0), bl_ + lin); g2l16(Bp1 + (k0), bl_ + lin + 2048); } while (0)
#define ASTAGE_G(k0, buf) do { u16* al_ = Al + (buf) * 4096; \
    g2l16(Ap0 + (k0), al_ + lin); g2l16(Ap1 + (k0), al_ + lin + 2048); } while (0)
#define ALOAD(k0) do { \
    a00 = *(const float4*)(Af0 + (k0)); a01 = *(const float4*)(Af0 + (k0) + 4); \
    a10 = *(const float4*)(Af1 + (k0)); a11 = *(const float4*)(Af1 + (k0) + 4); } while (0)
#define AWRITE(buf) do { u16* al_ = Al + (buf) * 4096; \
    union { u32 d[4]; s8v v; } ua, ub; \
    ua.d[0] = cvtpk(a00.x, a00.y); ua.d[1] = cvtpk(a00.z, a00.w); \
    ua.d[2] = cvtpk(a01.x, a01.y); ua.d[3] = cvtpk(a01.z, a01.w); \
    ub.d[0] = cvtpk(a10.x, a10.y); ub.d[1] = cvtpk(a10.z, a10.w); \
    ub.d[2] = cvtpk(a11.x, a11.y); ub.d[3] = cvtpk(a11.z, a11.w); \
    *(s8v*)(al_ + lin) = ua.v; *(s8v*)(al_ + lin + 2048) = ub.v; } while (0)

  if constexpr (F32A) { ALOAD(0); BSTAGE(0, 0); AWRITE(0); }
  else { ASTAGE_G(0, 0); BSTAGE(0, 0); }

  int nk = K >> 5;
  int swq8 = (quad ^ ((l16 >> 1) & 3)) * 8;        // read-side chunk, loop-invariant
  for (int t = 0; t < nk; ++t) {
    __syncthreads();                               // drains prefetch (vmcnt+lgkm) + dbuf reuse
    int nxt = (t + 1) * 32, nbuf = (t + 1) & 1;
    if (t + 1 < nk) {
      if constexpr (F32A) ALOAD(nxt); else ASTAGE_G(nxt, nbuf);
      BSTAGE(nxt, nbuf);
    }
    const u16* al = Al + (t & 1) * 4096;
    const u16* bl = Bl + (t & 1) * 4096;
    s8v af[4], bfr[4];
    #pragma unroll
    for (int i = 0; i < 4; i++) af[i] = *(const s8v*)(al + (wm + i * 16 + l16) * 32 + swq8);
    #pragma unroll
    for (int j = 0; j < 4; j++) bfr[j] = *(const s8v*)(bl + (wn + j * 16 + l16) * 32 + swq8);
    #pragma unroll
    for (int i = 0; i < 4; i++)
      #pragma unroll
      for (int j = 0; j < 4; j++)
        acc[i][j] = __builtin_amdgcn_mfma_f32_16x16x32_bf16(af[i], bfr[j], acc[i][j], 0, 0, 0);
    if constexpr (F32A) { if (t + 1 < nk) AWRITE(nbuf); }   // lands after MFMA cluster
  }
#undef BSTAGE
#undef ASTAGE_G
#undef ALOAD
#undef AWRITE
  #pragma unroll
  for (int i = 0; i < 4; i++) {
    int rbase = mb + wm + i * 16 + quad * 4;
    #pragma unroll
    for (int j = 0; j < 4; j++) {
      int col = nb + wn + j * 16 + l16;
      if (MODE == 0) {
        u16* Cb = (u16*)C0;
        #pragma unroll
        for (int r = 0; r < 4; r++) Cb[(size_t)(rbase + r) * N + col] = f2bf(acc[i][j][r] * oscale);
      } else if (MODE == 1) {
        float* Cf = (float*)C0;
        #pragma unroll
        for (int r = 0; r < 4; r++) Cf[(size_t)(rbase + r) * N + col] = acc[i][j][r] + bias[col];
      } else {
        if (col < 512) {                  // K projection -> Kb [b*NC+t][512]
          u16* Kb = (u16*)C0;
          #pragma unroll
          for (int r = 0; r < 4; r++) Kb[(size_t)(rbase + r) * 512 + col] = f2bf(acc[i][j][r]);
        } else {                          // V projection -> Vt, transposed + key-permuted
          u16* Vt = (u16*)C1;
          int hd = col - 512, h = hd >> 6, d = hd & 63;
          int bb = rbase >> 10, tl = rbase & 1023;
          int tbase = tl & ~63, a0 = tl & 63;          // a0 = quad*4-aligned key-local idx
          int pb = (a0 & 32) + ((a0 & 15) >> 2) * 8 + (((a0 >> 4) & 1) << 2);
          uint2 ov;
          ov.x = pack2(acc[i][j][0], acc[i][j][1]);
          ov.y = pack2(acc[i][j][2], acc[i][j][3]);
          *(uint2*)(Vt + ((size_t)(bb * NH + h) * DH + d) * NC + tbase + pb) = ov;
        }
      }
    }
  }
}

// ---------------- fused QKV projection, fp32 A direct (cast fused), KV-first ----------------
__global__ __launch_bounds__(256, 3) void proj_all(const float* __restrict__ x, const float* __restrict__ ctx,
                                                   const u16* __restrict__ wqT, const u16* __restrict__ wkvT,
                                                   u16* __restrict__ Qb, u16* __restrict__ Kb,
                                                   u16* __restrict__ Vtb, float qscale) {
  __shared__ alignas(16) u16 Al[2][128][32];
  __shared__ alignas(16) u16 Bl[2][128][32];
  int bx = blockIdx.x;
  if (bx < 256) {  // KV projection first (24 K-steps, longest-job-first): M=4096, N=1024, K=768
    gemm_body<2, true>(ctx, wkvT, Kb, Vtb, nullptr, 1024, 768, 1.0f, bx & 7, bx >> 3,
                       (u16*)Al, (u16*)Bl);
  } else {         // Q projection: M=16384, N=512, K=512
    int bi = bx - 256;
    gemm_body<0, true>(x, wqT, Qb, nullptr, nullptr, 512, 512, qscale, bi & 3, bi >> 2,
                       (u16*)Al, (u16*)Bl);
  }
}

// ---------------- output projection (fp32 out + bias) ----------------
__global__ __launch_bounds__(256, 2) void outproj(const u16* __restrict__ Ob, const u16* __restrict__ woT,
                                                  float* __restrict__ out, const float* __restrict__ bo) {
  __shared__ alignas(16) u16 Al[2][128][32];
  __shared__ alignas(16) u16 Bl[2][128][32];
  gemm_body<1, false>(Ob, woT, out, nullptr, bo, 512, 512, 1.0f, blockIdx.x, blockIdx.y,
                      (u16*)Al, (u16*)Bl);
}

// ---------------- flash cross-attention: 32 q/wave, 64-key tiles, 4 blocks/CU ----------------
// (unchanged from R1: MFMA-ones denominator, cvt_pk packs, pipelined chunks + setprio)
__global__ __launch_bounds__(256, 4) void attn(const u16* __restrict__ Q, const u16* __restrict__ Kb,
                                               const u16* __restrict__ Vt, u16* __restrict__ O) {
  __shared__ alignas(16) u16 Kl[2][64][64];   // 16 KB
  __shared__ alignas(16) u16 Vl[2][64][64];   // 16 KB
  int qt = blockIdx.x, h = blockIdx.y, b = blockIdx.z;
  int tid = threadIdx.x, wave = tid >> 6, lane = tid & 63, quad = lane >> 4, l16 = lane & 15;
  int q0 = qt * 128 + wave * 32;
  int x7 = l16 & 7;

  int kr = tid >> 3, kc = (tid & 7) ^ (kr & 7);
  const u16* kg = Kb + ((size_t)b * NC + kr) * 512 + h * DH + kc * 8;
  const u16* vg = Vt + ((size_t)(b * NH + h) * DH + kr) * NC + kc * 8;

#define ASTAGE(kt, buf) do { \
    const u16* kg_ = kg + (size_t)(kt) * 64 * 512; \
    const u16* vg_ = vg + (kt) * 64; \
    u16* kl_ = (u16*)Kl + (buf) * 4096; u16* vl_ = (u16*)Vl + (buf) * 4096; \
    g2l16(kg_,            kl_ + tid * 8); \
    g2l16(kg_ + 32 * 512, kl_ + (tid + 256) * 8); \
    g2l16(vg_,            vl_ + tid * 8); \
    g2l16(vg_ + 32 * NC,  vl_ + (tid + 256) * 8); } while (0)

  s8v aq[2][2];
  {
    const u16* Qp = Q + ((size_t)b * NQ + q0 + l16) * DI + h * DH + quad * 8;
    #pragma unroll
    for (int n = 0; n < 2; n++) {
      aq[n][0] = *(const s8v*)(Qp + (size_t)n * 16 * DI);
      aq[n][1] = *(const s8v*)(Qp + (size_t)n * 16 * DI + 32);
    }
  }
  s8v vones;
  #pragma unroll
  for (int i = 0; i < 8; i++) vones[i] = (short)0x3F80;

  f4v oacc[4][2];
  f4v lacc[2];
  #pragma unroll
  for (int d = 0; d < 4; d++)
    #pragma unroll
    for (int n = 0; n < 2; n++) oacc[d][n] = (f4v){0.f, 0.f, 0.f, 0.f};
  #pragma unroll
  for (int n = 0; n < 2; n++) lacc[n] = (f4v){0.f, 0.f, 0.f, 0.f};

  ASTAGE(0, 0);
  for (int kt = 0; kt < NC / 64; ++kt) {
    int buf = kt & 1;
    __syncthreads();
    if (kt + 1 < NC / 64) ASTAGE(kt + 1, buf ^ 1);
    const u16* kb = (const u16*)Kl + buf * 4096;
    const u16* vb = (const u16*)Vl + buf * 4096;

    f4v S0[2][2], S1[2][2];
    #pragma unroll
    for (int mi = 0; mi < 2; mi++)
      #pragma unroll
      for (int n = 0; n < 2; n++) { S0[mi][n] = (f4v){0.f,0.f,0.f,0.f}; S1[mi][n] = (f4v){0.f,0.f,0.f,0.f}; }
    __builtin_amdgcn_s_setprio(1);
    #pragma unroll
    for (int cd = 0; cd < 2; cd++) {
      int ch = ((4 * cd + quad) ^ x7) * 8;
      s8v k00 = *(const s8v*)(kb + (l16     ) * 64 + ch);
      s8v k01 = *(const s8v*)(kb + (l16 + 16) * 64 + ch);
      #pragma unroll
      for (int n = 0; n < 2; n++) {
        S0[0][n] = __builtin_amdgcn_mfma_f32_16x16x32_bf16(k00, aq[n][cd], S0[0][n], 0, 0, 0);
        S0[1][n] = __builtin_amdgcn_mfma_f32_16x16x32_bf16(k01, aq[n][cd], S0[1][n], 0, 0, 0);
      }
      s8v k10 = *(const s8v*)(kb + (l16 + 32) * 64 + ch);
      s8v k11 = *(const s8v*)(kb + (l16 + 48) * 64 + ch);
      #pragma unroll
      for (int n = 0; n < 2; n++) {
        S1[0][n] = __builtin_amdgcn_mfma_f32_16x16x32_bf16(k10, aq[n][cd], S1[0][n], 0, 0, 0);
        S1[1][n] = __builtin_amdgcn_mfma_f32_16x16x32_bf16(k11, aq[n][cd], S1[1][n], 0, 0, 0);
      }
    }
    __builtin_amdgcn_s_setprio(0);

    s8v pf0[2];
    #pragma unroll
    for (int n = 0; n < 2; n++) {
      float p00 = EXP2(S0[0][n][0]), p01 = EXP2(S0[0][n][1]), p02 = EXP2(S0[0][n][2]), p03 = EXP2(S0[0][n][3]);
      float p10 = EXP2(S0[1][n][0]), p11 = EXP2(S0[1][n][1]), p12 = EXP2(S0[1][n][2]), p13 = EXP2(S0[1][n][3]);
      union { u32 d[4]; s8v v; } u;
      u.d[0] = cvtpk(p00, p01); u.d[1] = cvtpk(p02, p03);
      u.d[2] = cvtpk(p10, p11); u.d[3] = cvtpk(p12, p13);
      pf0[n] = u.v;
    }
    __builtin_amdgcn_s_setprio(1);
    #pragma unroll
    for (int n = 0; n < 2; n++)
      lacc[n] = __builtin_amdgcn_mfma_f32_16x16x32_bf16(vones, pf0[n], lacc[n], 0, 0, 0);
    #pragma unroll
    for (int d = 0; d < 4; d++) {
      int ch = (quad ^ x7) * 8;
      s8v vf = *(const s8v*)(vb + (d * 16 + l16) * 64 + ch);
      #pragma unroll
      for (int n = 0; n < 2; n++)
        oacc[d][n] = __builtin_amdgcn_mfma_f32_16x16x32_bf16(vf, pf0[n], oacc[d][n], 0, 0, 0);
    }
    __builtin_amdgcn_s_setprio(0);

    s8v pf1[2];
    #pragma unroll
    for (int n = 0; n < 2; n++) {
      float p00 = EXP2(S1[0][n][0]), p01 = EXP2(S1[0][n][1]), p02 = EXP2(S1[0][n][2]), p03 = EXP2(S1[0][n][3]);
      float p10 = EXP2(S1[1][n][0]), p11 = EXP2(S1[1][n][1]), p12 = EXP2(S1[1][n][2]), p13 = EXP2(S1[1][n][3]);
      union { u32 d[4]; s8v v; } u;
      u.d[0] = cvtpk(p00, p01); u.d[1] = cvtpk(p02, p03);
      u.d[2] = cvtpk(p10, p11); u.d[3] = cvtpk(p12, p13);
      pf1[n] = u.v;
    }
    __builtin_amdgcn_s_setprio(1);
    #pragma unroll
    for (int n = 0; n < 2; n++)
      lacc[n] = __builtin_amdgcn_mfma_f32_16x16x32_bf16(vones, pf1[n], lacc[n], 0, 0, 0);
    #pragma unroll
    for (int d = 0; d < 4; d++) {
      int ch = ((4 + quad) ^ x7) * 8;
      s8v vf = *(const s8v*)(vb + (d * 16 + l16) * 64 + ch);
      #pragma unroll
      for (int n = 0; n < 2; n++)
        oacc[d][n] = __builtin_amdgcn_mfma_f32_16x16x32_bf16(vf, pf1[n], oacc[d][n], 0, 0, 0);
    }
    __builtin_amdgcn_s_setprio(0);
  }
#undef ASTAGE

  float inv[2];
  #pragma unroll
  for (int n = 0; n < 2; n++) inv[n] = 1.0f / lacc[n][0];

  #pragma unroll
  for (int d = 0; d < 4; d++)
    #pragma unroll
    for (int n = 0; n < 2; n++) {
      int q = q0 + n * 16 + l16;
      uint2 ov;
      ov.x = cvtpk(oacc[d][n][0] * inv[n], oacc[d][n][1] * inv[n]);
      ov.y = cvtpk(oacc[d][n][2] * inv[n], oacc[d][n][3] * inv[n]);
      *(uint2*)(O + ((size_t)b * NQ + q) * DI + h * DH + d * 16 + quad * 4) = ov;
    }
}

extern "C" void kernel_launch(void* const* d_in, const int* in_sizes, int n_in,
                              void* d_out, int out_size, void* d_ws, size_t ws_size,
                              hipStream_t stream) {
  const float* x   = (const float*)d_in[0];
  const float* ctx = (const float*)d_in[1];
  const float* Wq  = (const float*)d_in[2];
  const float* Wk  = (const float*)d_in[3];
  const float* Wv  = (const float*)d_in[4];
  const float* Wo  = (const float*)d_in[5];
  const float* bo  = (const float*)d_in[6];
  float* out = (float*)d_out;

  u16* w    = (u16*)d_ws;                // workspace layout (bf16 elems)
  u16* wqT  = w;                         // 262144
  u16* wkvT = wqT  + 262144;             // 786432 (Wk^T rows 0-511, Wv^T rows 512-1023)
  u16* woT  = wkvT + 786432;             // 262144
  u16* Qb   = woT  + 262144;             // 8388608 (pre-scaled by 0.125*log2e)
  u16* Kbuf = Qb   + 8388608;            // 2097152 ([b*1024+t][512])
  u16* Vtb  = Kbuf + 2097152;            // 2097152 (key-permuted V^T)
  u16* Ob   = Vtb  + 2097152;            // 8388608

  const float qscale = 0.125f * 1.44269504f;  // softmax scale + log2(e) folded into Q

  prep<<<384, 256, 0, stream>>>(Wq, Wk, Wv, Wo, wqT, wkvT, woT);
  proj_all<<<768, 256, 0, stream>>>(x, ctx, wqT, wkvT, Qb, Kbuf, Vtb, qscale);
  attn<<<dim3(32, 8, 4), 256, 0, stream>>>(Qb, Kbuf, Vtb, Ob);
  outproj<<<dim3(4, 128), 256, 0, stream>>>(Ob, woT, out, bo);
}

// Round 4
// 188.605 us; speedup vs baseline: 1.0302x; 1.0302x over previous
//
#include <hip/hip_runtime.h>
#include <math.h>

typedef __attribute__((ext_vector_type(8))) short s8v;   // 8 x bf16 (4 VGPRs) — MFMA A/B frag
typedef __attribute__((ext_vector_type(4))) float f4v;   // 4 x fp32 — MFMA C/D frag
typedef unsigned short u16;
typedef unsigned int u32;

constexpr int Bsz = 4, NQ = 4096, NC = 1024, NH = 8, DH = 64, DI = 512, DC = 768;

__device__ __forceinline__ u16 f2bf(float f) {
  union { float f; u32 u; } v; v.f = f;
  u32 r = v.u + 0x7fff + ((v.u >> 16) & 1);  // RNE
  return (u16)(r >> 16);
}

// pack two f32 -> two bf16 in one dword (round-half-up) — used in V epilogue
__device__ __forceinline__ u32 pack2(float a, float b) {
  union { float f; u32 u; } ua, ub; ua.f = a; ub.f = b;
#if __has_builtin(__builtin_amdgcn_perm)
  return __builtin_amdgcn_perm(ub.u + 0x8000u, ua.u + 0x8000u, 0x07060302u);
#else
  return ((ub.u + 0x8000u) & 0xffff0000u) | ((ua.u + 0x8000u) >> 16);
#endif
}

// single-instruction RNE pack (v_cvt_pk_bf16_f32): lo16=bf16(a), hi16=bf16(b)
__device__ __forceinline__ u32 cvtpk(float a, float b) {
  u32 r;
  asm("v_cvt_pk_bf16_f32 %0, %1, %2" : "=v"(r) : "v"(a), "v"(b));
  return r;
}

#if __has_builtin(__builtin_amdgcn_exp2f)
#define EXP2(x) __builtin_amdgcn_exp2f(x)
#else
#define EXP2(x) exp2f(x)
#endif

// async global->LDS, 16B per lane (m97 pattern)
__device__ __forceinline__ void g2l16(const void* g, void* l) {
  __builtin_amdgcn_global_load_lds((const __attribute__((address_space(1))) u32*)g,
                                   (__attribute__((address_space(3))) u32*)l, 16, 0, 0);
}

// ---------------- prep: weight transposes only ----------------
__global__ __launch_bounds__(256) void prep(const float* __restrict__ Wq, const float* __restrict__ Wk,
                                            const float* __restrict__ Wv, const float* __restrict__ Wo,
                                            u16* __restrict__ wqT, u16* __restrict__ wkvT,
                                            u16* __restrict__ woT) {
  int idx = blockIdx.x;                   // [0,384)
  int z = idx / 96, rem = idx % 96, kx = rem % 12, ny = rem / 12;
  const float* src; u16* dst; int K; const int N = 512;
  if (z == 0)      { src = Wq; dst = wqT;              K = 512; }
  else if (z == 1) { src = Wk; dst = wkvT;             K = 768; }
  else if (z == 2) { src = Wv; dst = wkvT + 512 * 768; K = 768; }
  else             { src = Wo; dst = woT;              K = 512; }
  int k0 = kx * 64, n0 = ny * 64;
  if (k0 >= K) return;
  __shared__ u16 t[64][65];
  int tid = threadIdx.x, jr = tid & 63, ir = tid >> 6;
  for (int it = 0; it < 16; ++it) { int i = it * 4 + ir; t[i][jr] = f2bf(src[(size_t)(k0 + i) * N + n0 + jr]); }
  __syncthreads();
  for (int it = 0; it < 16; ++it) { int i = it * 4 + ir; dst[(size_t)(n0 + i) * K + k0 + jr] = t[jr][i]; }
}

// ---------------- shared GEMM body: 128x128 tile, BK=32 ----------------
// R4 (= R3 with the token-paste bug fixed): 3-buffer LDS pipeline, prefetch depth 2,
// counted vmcnt + raw s_barrier (T3/T4). Loop top waits only the tile being read
// (vmcnt(6) F32A / vmcnt(4) bf16) so the next tile's loads stay in flight across the
// barrier; tail iterations drain to vmcnt(0).
// XOR-chunk swizzle (pre-swizzled SOURCE, linear LDS dest; read chunk = quad^((l16>>1)&3))
// keeps ds_read_b128 conflict-free (R2-verified: SQ_LDS_BANK_CONFLICT = 0).
// F32A: A fp32 in global; reg-stage float4 -> cvt_pk -> ds_write (T14 split, 2 reg sets).
template <int MODE, bool F32A>
__device__ __forceinline__ void gemm_body(const void* __restrict__ Av, const u16* __restrict__ Bt,
                                          void* __restrict__ C0, void* __restrict__ C1,
                                          const float* __restrict__ bias, int N, int K,
                                          float oscale, int nbx, int mby,
                                          u16* Al, u16* Bl) {   // Al/Bl: [3][128][32]
  int mb = mby * 128, nb = nbx * 128;
  int tid = threadIdx.x, lane = tid & 63, quad = lane >> 4, l16 = lane & 15, wave = tid >> 6;
  int wm = (wave >> 1) * 64, wn = (wave & 1) * 64;
  f4v acc[4][4];
  #pragma unroll
  for (int i = 0; i < 4; i++)
    #pragma unroll
    for (int j = 0; j < 4; j++) acc[i][j] = (f4v){0.f, 0.f, 0.f, 0.f};

  int r0 = tid >> 2;
  int cs = ((tid & 3) ^ ((r0 >> 1) & 3)) * 8;     // swizzled source chunk -> element offset
  int lin = tid * 8;                               // linear LDS dest (elements)
  const u16* Bp0 = Bt + (size_t)(nb + r0) * K + cs;
  const u16* Bp1 = Bp0 + (size_t)64 * K;
  const float* Af0 = nullptr; const float* Af1 = nullptr;
  const u16* Ap0 = nullptr; const u16* Ap1 = nullptr;
  if constexpr (F32A) {
    Af0 = (const float*)Av + (size_t)(mb + r0) * K + cs;
    Af1 = Af0 + (size_t)64 * K;
  } else {
    Ap0 = (const u16*)Av + (size_t)(mb + r0) * K + cs;
    Ap1 = Ap0 + (size_t)64 * K;
  }
  float4 ra[4], rb[4];                             // 2 in-flight fp32 A reg sets (literal idx only)

#define BSTG(k0, bl_) do { g2l16(Bp0 + (k0), (bl_) + lin); g2l16(Bp1 + (k0), (bl_) + lin + 2048); } while (0)
#define ASTG(k0, al_) do { g2l16(Ap0 + (k0), (al_) + lin); g2l16(Ap1 + (k0), (al_) + lin + 2048); } while (0)
#define ALD(k0, s) do { \
    s[0] = *(const float4*)(Af0 + (k0)); s[1] = *(const float4*)(Af0 + (k0) + 4); \
    s[2] = *(const float4*)(Af1 + (k0)); s[3] = *(const float4*)(Af1 + (k0) + 4); } while (0)
#define AWR(s, al_) do { union { u32 d[4]; s8v v; } ua, ub; \
    ua.d[0] = cvtpk(s[0].x, s[0].y); ua.d[1] = cvtpk(s[0].z, s[0].w); \
    ua.d[2] = cvtpk(s[1].x, s[1].y); ua.d[3] = cvtpk(s[1].z, s[1].w); \
    ub.d[0] = cvtpk(s[2].x, s[2].y); ub.d[1] = cvtpk(s[2].z, s[2].w); \
    ub.d[2] = cvtpk(s[3].x, s[3].y); ub.d[3] = cvtpk(s[3].z, s[3].w); \
    *(s8v*)((al_) + lin) = ua.v; *(s8v*)((al_) + lin + 2048) = ub.v; } while (0)

  u16 *Ar = Al, *Aw = Al + 4096, *As = Al + 8192;
  u16 *Br = Bl, *Bw = Bl + 4096, *Bs = Bl + 8192;
  if constexpr (F32A) {
    ALD(0, ra); BSTG(0, Br); AWR(ra, Ar);          // tile 0: A via regs->LDS (implicit vmcnt wait)
    ALD(32, rb); BSTG(32, Bw);                     // tile 1 in flight
  } else {
    ASTG(0, Ar); BSTG(0, Br);
    ASTG(32, Aw); BSTG(32, Bw);
  }

  int nk = K >> 5;
  int swq8 = (quad ^ ((l16 >> 1) & 3)) * 8;        // read-side chunk, loop-invariant
  for (int t = 0; t < nk; ++t) {
    // counted drain: only tile t's staging must complete; tile t+1 stays in flight.
    if (t + 1 < nk) {
      if constexpr (F32A) asm volatile("s_waitcnt vmcnt(6) lgkmcnt(0)" ::: "memory");
      else                asm volatile("s_waitcnt vmcnt(4) lgkmcnt(0)" ::: "memory");
    } else {
      asm volatile("s_waitcnt vmcnt(0) lgkmcnt(0)" ::: "memory");
    }
    __builtin_amdgcn_s_barrier();
    asm volatile("" ::: "memory");                 // no loads hoist above the barrier
    __builtin_amdgcn_sched_barrier(0);

    if (t + 2 < nk) {
      int nxt = (t + 2) * 32;
      if constexpr (F32A) {
        if (t & 1) { ALD(nxt, rb); } else { ALD(nxt, ra); }   // set (t+2)&1
        BSTG(nxt, Bs);
      } else {
        ASTG(nxt, As); BSTG(nxt, Bs);
      }
    }

    s8v af[4], bfr[4];
    #pragma unroll
    for (int i = 0; i < 4; i++) af[i] = *(const s8v*)(Ar + (wm + i * 16 + l16) * 32 + swq8);
    #pragma unroll
    for (int j = 0; j < 4; j++) bfr[j] = *(const s8v*)(Br + (wn + j * 16 + l16) * 32 + swq8);
    #pragma unroll
    for (int i = 0; i < 4; i++)
      #pragma unroll
      for (int j = 0; j < 4; j++)
        acc[i][j] = __builtin_amdgcn_mfma_f32_16x16x32_bf16(af[i], bfr[j], acc[i][j], 0, 0, 0);

    if constexpr (F32A) {
      if (t + 1 < nk) {                            // write tile t+1's A after the MFMA cluster
        if (t & 1) { AWR(ra, Aw); } else { AWR(rb, Aw); }     // set (t+1)&1
      }
    }
    u16* tA = Ar; Ar = Aw; Aw = As; As = tA;       // rotate read/write/stage buffers
    u16* tB = Br; Br = Bw; Bw = Bs; Bs = tB;
  }
#undef BSTG
#undef ASTG
#undef ALD
#undef AWR
  #pragma unroll
  for (int i = 0; i < 4; i++) {
    int rbase = mb + wm + i * 16 + quad * 4;
    #pragma unroll
    for (int j = 0; j < 4; j++) {
      int col = nb + wn + j * 16 + l16;
      if (MODE == 0) {
        u16* Cb = (u16*)C0;
        #pragma unroll
        for (int r = 0; r < 4; r++) Cb[(size_t)(rbase + r) * N + col] = f2bf(acc[i][j][r] * oscale);
      } else if (MODE == 1) {
        float* Cf = (float*)C0;
        #pragma unroll
        for (int r = 0; r < 4; r++) Cf[(size_t)(rbase + r) * N + col] = acc[i][j][r] + bias[col];
      } else {
        if (col < 512) {                  // K projection -> Kb [b*NC+t][512]
          u16* Kb = (u16*)C0;
          #pragma unroll
          for (int r = 0; r < 4; r++) Kb[(size_t)(rbase + r) * 512 + col] = f2bf(acc[i][j][r]);
        } else {                          // V projection -> Vt, transposed + key-permuted
          u16* Vt = (u16*)C1;
          int hd = col - 512, h = hd >> 6, d = hd & 63;
          int bb = rbase >> 10, tl = rbase & 1023;
          int tbase = tl & ~63, a0 = tl & 63;          // a0 = quad*4-aligned key-local idx
          int pb = (a0 & 32) + ((a0 & 15) >> 2) * 8 + (((a0 >> 4) & 1) << 2);
          uint2 ov;
          ov.x = pack2(acc[i][j][0], acc[i][j][1]);
          ov.y = pack2(acc[i][j][2], acc[i][j][3]);
          *(uint2*)(Vt + ((size_t)(bb * NH + h) * DH + d) * NC + tbase + pb) = ov;
        }
      }
    }
  }
}

// ---------------- fused QKV projection, fp32 A direct, XCD-chunked swizzle ----------------
// blockIdx -> XCD assumed bx%8 (measured round-robin); each XCD gets 32 KV + 64 Q blocks
// (balanced 1792 K-step-units/XCD). Consecutive blocks within an XCD share A-panels
// (per-XCD x slice = 4 MB ~= L2), so A re-reads become L2 hits instead of HBM misses.
__global__ __launch_bounds__(256, 3) void proj_all(const float* __restrict__ x, const float* __restrict__ ctx,
                                                   const u16* __restrict__ wqT, const u16* __restrict__ wkvT,
                                                   u16* __restrict__ Qb, u16* __restrict__ Kb,
                                                   u16* __restrict__ Vtb, float qscale) {
  __shared__ alignas(16) u16 Al[3][128][32];
  __shared__ alignas(16) u16 Bl[3][128][32];
  int bx = blockIdx.x;
  int xcd = bx & 7, off = bx >> 3;        // off in [0,96)
  if (off < 32) {  // KV projection (24 K-steps, longest-first within XCD): M=4096, N=1024, K=768
    int bi = xcd * 32 + off;              // [0,256)
    gemm_body<2, true>(ctx, wkvT, Kb, Vtb, nullptr, 1024, 768, 1.0f, bi & 7, bi >> 3,
                       (u16*)Al, (u16*)Bl);
  } else {         // Q projection: M=16384, N=512, K=512
    int bi = xcd * 64 + (off - 32);       // [0,512)
    gemm_body<0, true>(x, wqT, Qb, nullptr, nullptr, 512, 512, qscale, bi & 3, bi >> 2,
                       (u16*)Al, (u16*)Bl);
  }
}

// ---------------- output projection (fp32 out + bias), XCD-chunked swizzle ----------------
__global__ __launch_bounds__(256, 3) void outproj(const u16* __restrict__ Ob, const u16* __restrict__ woT,
                                                  float* __restrict__ out, const float* __restrict__ bo) {
  __shared__ alignas(16) u16 Al[3][128][32];
  __shared__ alignas(16) u16 Bl[3][128][32];
  int bx = blockIdx.x;
  int idx = (bx & 7) * 64 + (bx >> 3);    // [0,512): same-XCD blocks share Ob panels
  gemm_body<1, false>(Ob, woT, out, nullptr, bo, 512, 512, 1.0f, idx & 3, idx >> 2,
                      (u16*)Al, (u16*)Bl);
}

// ---------------- flash cross-attention: 32 q/wave, 64-key tiles, 4 blocks/CU ----------------
// (unchanged from R1: MFMA-ones denominator, cvt_pk packs, pipelined chunks + setprio)
__global__ __launch_bounds__(256, 4) void attn(const u16* __restrict__ Q, const u16* __restrict__ Kb,
                                               const u16* __restrict__ Vt, u16* __restrict__ O) {
  __shared__ alignas(16) u16 Kl[2][64][64];   // 16 KB
  __shared__ alignas(16) u16 Vl[2][64][64];   // 16 KB
  int qt = blockIdx.x, h = blockIdx.y, b = blockIdx.z;
  int tid = threadIdx.x, wave = tid >> 6, lane = tid & 63, quad = lane >> 4, l16 = lane & 15;
  int q0 = qt * 128 + wave * 32;
  int x7 = l16 & 7;

  int kr = tid >> 3, kc = (tid & 7) ^ (kr & 7);
  const u16* kg = Kb + ((size_t)b * NC + kr) * 512 + h * DH + kc * 8;
  const u16* vg = Vt + ((size_t)(b * NH + h) * DH + kr) * NC + kc * 8;

#define ASTAGE(kt, buf) do { \
    const u16* kg_ = kg + (size_t)(kt) * 64 * 512; \
    const u16* vg_ = vg + (kt) * 64; \
    u16* kl_ = (u16*)Kl + (buf) * 4096; u16* vl_ = (u16*)Vl + (buf) * 4096; \
    g2l16(kg_,            kl_ + tid * 8); \
    g2l16(kg_ + 32 * 512, kl_ + (tid + 256) * 8); \
    g2l16(vg_,            vl_ + tid * 8); \
    g2l16(vg_ + 32 * NC,  vl_ + (tid + 256) * 8); } while (0)

  s8v aq[2][2];
  {
    const u16* Qp = Q + ((size_t)b * NQ + q0 + l16) * DI + h * DH + quad * 8;
    #pragma unroll
    for (int n = 0; n < 2; n++) {
      aq[n][0] = *(const s8v*)(Qp + (size_t)n * 16 * DI);
      aq[n][1] = *(const s8v*)(Qp + (size_t)n * 16 * DI + 32);
    }
  }
  s8v vones;
  #pragma unroll
  for (int i = 0; i < 8; i++) vones[i] = (short)0x3F80;

  f4v oacc[4][2];
  f4v lacc[2];
  #pragma unroll
  for (int d = 0; d < 4; d++)
    #pragma unroll
    for (int n = 0; n < 2; n++) oacc[d][n] = (f4v){0.f, 0.f, 0.f, 0.f};
  #pragma unroll
  for (int n = 0; n < 2; n++) lacc[n] = (f4v){0.f, 0.f, 0.f, 0.f};

  ASTAGE(0, 0);
  for (int kt = 0; kt < NC / 64; ++kt) {
    int buf = kt & 1;
    __syncthreads();
    if (kt + 1 < NC / 64) ASTAGE(kt + 1, buf ^ 1);
    const u16* kb = (const u16*)Kl + buf * 4096;
    const u16* vb = (const u16*)Vl + buf * 4096;

    f4v S0[2][2], S1[2][2];
    #pragma unroll
    for (int mi = 0; mi < 2; mi++)
      #pragma unroll
      for (int n = 0; n < 2; n++) { S0[mi][n] = (f4v){0.f,0.f,0.f,0.f}; S1[mi][n] = (f4v){0.f,0.f,0.f,0.f}; }
    __builtin_amdgcn_s_setprio(1);
    #pragma unroll
    for (int cd = 0; cd < 2; cd++) {
      int ch = ((4 * cd + quad) ^ x7) * 8;
      s8v k00 = *(const s8v*)(kb + (l16     ) * 64 + ch);
      s8v k01 = *(const s8v*)(kb + (l16 + 16) * 64 + ch);
      #pragma unroll
      for (int n = 0; n < 2; n++) {
        S0[0][n] = __builtin_amdgcn_mfma_f32_16x16x32_bf16(k00, aq[n][cd], S0[0][n], 0, 0, 0);
        S0[1][n] = __builtin_amdgcn_mfma_f32_16x16x32_bf16(k01, aq[n][cd], S0[1][n], 0, 0, 0);
      }
      s8v k10 = *(const s8v*)(kb + (l16 + 32) * 64 + ch);
      s8v k11 = *(const s8v*)(kb + (l16 + 48) * 64 + ch);
      #pragma unroll
      for (int n = 0; n < 2; n++) {
        S1[0][n] = __builtin_amdgcn_mfma_f32_16x16x32_bf16(k10, aq[n][cd], S1[0][n], 0, 0, 0);
        S1[1][n] = __builtin_amdgcn_mfma_f32_16x16x32_bf16(k11, aq[n][cd], S1[1][n], 0, 0, 0);
      }
    }
    __builtin_amdgcn_s_setprio(0);

    s8v pf0[2];
    #pragma unroll
    for (int n = 0; n < 2; n++) {
      float p00 = EXP2(S0[0][n][0]), p01 = EXP2(S0[0][n][1]), p02 = EXP2(S0[0][n][2]), p03 = EXP2(S0[0][n][3]);
      float p10 = EXP2(S0[1][n][0]), p11 = EXP2(S0[1][n][1]), p12 = EXP2(S0[1][n][2]), p13 = EXP2(S0[1][n][3]);
      union { u32 d[4]; s8v v; } u;
      u.d[0] = cvtpk(p00, p01); u.d[1] = cvtpk(p02, p03);
      u.d[2] = cvtpk(p10, p11); u.d[3] = cvtpk(p12, p13);
      pf0[n] = u.v;
    }
    __builtin_amdgcn_s_setprio(1);
    #pragma unroll
    for (int n = 0; n < 2; n++)
      lacc[n] = __builtin_amdgcn_mfma_f32_16x16x32_bf16(vones, pf0[n], lacc[n], 0, 0, 0);
    #pragma unroll
    for (int d = 0; d < 4; d++) {
      int ch = (quad ^ x7) * 8;
      s8v vf = *(const s8v*)(vb + (d * 16 + l16) * 64 + ch);
      #pragma unroll
      for (int n = 0; n < 2; n++)
        oacc[d][n] = __builtin_amdgcn_mfma_f32_16x16x32_bf16(vf, pf0[n], oacc[d][n], 0, 0, 0);
    }
    __builtin_amdgcn_s_setprio(0);

    s8v pf1[2];
    #pragma unroll
    for (int n = 0; n < 2; n++) {
      float p00 = EXP2(S1[0][n][0]), p01 = EXP2(S1[0][n][1]), p02 = EXP2(S1[0][n][2]), p03 = EXP2(S1[0][n][3]);
      float p10 = EXP2(S1[1][n][0]), p11 = EXP2(S1[1][n][1]), p12 = EXP2(S1[1][n][2]), p13 = EXP2(S1[1][n][3]);
      union { u32 d[4]; s8v v; } u;
      u.d[0] = cvtpk(p00, p01); u.d[1] = cvtpk(p02, p03);
      u.d[2] = cvtpk(p10, p11); u.d[3] = cvtpk(p12, p13);
      pf1[n] = u.v;
    }
    __builtin_amdgcn_s_setprio(1);
    #pragma unroll
    for (int n = 0; n < 2; n++)
      lacc[n] = __builtin_amdgcn_mfma_f32_16x16x32_bf16(vones, pf1[n], lacc[n], 0, 0, 0);
    #pragma unroll
    for (int d = 0; d < 4; d++) {
      int ch = ((4 + quad) ^ x7) * 8;
      s8v vf = *(const s8v*)(vb + (d * 16 + l16) * 64 + ch);
      #pragma unroll
      for (int n = 0; n < 2; n++)
        oacc[d][n] = __builtin_amdgcn_mfma_f32_16x16x32_bf16(vf, pf1[n], oacc[d][n], 0, 0, 0);
    }
    __builtin_amdgcn_s_setprio(0);
  }
#undef ASTAGE

  float inv[2];
  #pragma unroll
  for (int n = 0; n < 2; n++) inv[n] = 1.0f / lacc[n][0];

  #pragma unroll
  for (int d = 0; d < 4; d++)
    #pragma unroll
    for (int n = 0; n < 2; n++) {
      int q = q0 + n * 16 + l16;
      uint2 ov;
      ov.x = cvtpk(oacc[d][n][0] * inv[n], oacc[d][n][1] * inv[n]);
      ov.y = cvtpk(oacc[d][n][2] * inv[n], oacc[d][n][3] * inv[n]);
      *(uint2*)(O + ((size_t)b * NQ + q) * DI + h * DH + d * 16 + quad * 4) = ov;
    }
}

extern "C" void kernel_launch(void* const* d_in, const int* in_sizes, int n_in,
                              void* d_out, int out_size, void* d_ws, size_t ws_size,
                              hipStream_t stream) {
  const float* x   = (const float*)d_in[0];
  const float* ctx = (const float*)d_in[1];
  const float* Wq  = (const float*)d_in[2];
  const float* Wk  = (const float*)d_in[3];
  const float* Wv  = (const float*)d_in[4];
  const float* Wo  = (const float*)d_in[5];
  const float* bo  = (const float*)d_in[6];
  float* out = (float*)d_out;

  u16* w    = (u16*)d_ws;                // workspace layout (bf16 elems)
  u16* wqT  = w;                         // 262144
  u16* wkvT = wqT  + 262144;             // 786432 (Wk^T rows 0-511, Wv^T rows 512-1023)
  u16* woT  = wkvT + 786432;             // 262144
  u16* Qb   = woT  + 262144;             // 8388608 (pre-scaled by 0.125*log2e)
  u16* Kbuf = Qb   + 8388608;            // 2097152 ([b*1024+t][512])
  u16* Vtb  = Kbuf + 2097152;            // 2097152 (key-permuted V^T)
  u16* Ob   = Vtb  + 2097152;            // 8388608

  const float qscale = 0.125f * 1.44269504f;  // softmax scale + log2(e) folded into Q

  prep<<<384, 256, 0, stream>>>(Wq, Wk, Wv, Wo, wqT, wkvT, woT);
  proj_all<<<768, 256, 0, stream>>>(x, ctx, wqT, wkvT, Qb, Kbuf, Vtb, qscale);
  attn<<<dim3(32, 8, 4), 256, 0, stream>>>(Qb, Kbuf, Vtb, Ob);
  outproj<<<512, 256, 0, stream>>>(Ob, woT, out, bo);
}

// Round 5
// 187.512 us; speedup vs baseline: 1.0362x; 1.0058x over previous
//
#include <hip/hip_runtime.h>
#include <math.h>

typedef __attribute__((ext_vector_type(8))) short s8v;   // 8 x bf16 (4 VGPRs) — MFMA A/B frag
typedef __attribute__((ext_vector_type(4))) float f4v;   // 4 x fp32 — MFMA C/D frag
typedef unsigned short u16;
typedef unsigned int u32;

constexpr int Bsz = 4, NQ = 4096, NC = 1024, NH = 8, DH = 64, DI = 512, DC = 768;

__device__ __forceinline__ u16 f2bf(float f) {
  union { float f; u32 u; } v; v.f = f;
  u32 r = v.u + 0x7fff + ((v.u >> 16) & 1);  // RNE
  return (u16)(r >> 16);
}

// pack two f32 -> two bf16 in one dword (round-half-up) — used in V epilogue
__device__ __forceinline__ u32 pack2(float a, float b) {
  union { float f; u32 u; } ua, ub; ua.f = a; ub.f = b;
#if __has_builtin(__builtin_amdgcn_perm)
  return __builtin_amdgcn_perm(ub.u + 0x8000u, ua.u + 0x8000u, 0x07060302u);
#else
  return ((ub.u + 0x8000u) & 0xffff0000u) | ((ua.u + 0x8000u) >> 16);
#endif
}

// single-instruction RNE pack (v_cvt_pk_bf16_f32): lo16=bf16(a), hi16=bf16(b)
__device__ __forceinline__ u32 cvtpk(float a, float b) {
  u32 r;
  asm("v_cvt_pk_bf16_f32 %0, %1, %2" : "=v"(r) : "v"(a), "v"(b));
  return r;
}

#if __has_builtin(__builtin_amdgcn_exp2f)
#define EXP2(x) __builtin_amdgcn_exp2f(x)
#else
#define EXP2(x) exp2f(x)
#endif

// async global->LDS, 16B per lane (m97 pattern)
__device__ __forceinline__ void g2l16(const void* g, void* l) {
  __builtin_amdgcn_global_load_lds((const __attribute__((address_space(1))) u32*)g,
                                   (__attribute__((address_space(3))) u32*)l, 16, 0, 0);
}

// ---------------- prep: weight transposes only ----------------
__global__ __launch_bounds__(256) void prep(const float* __restrict__ Wq, const float* __restrict__ Wk,
                                            const float* __restrict__ Wv, const float* __restrict__ Wo,
                                            u16* __restrict__ wqT, u16* __restrict__ wkvT,
                                            u16* __restrict__ woT) {
  int idx = blockIdx.x;                   // [0,384)
  int z = idx / 96, rem = idx % 96, kx = rem % 12, ny = rem / 12;
  const float* src; u16* dst; int K; const int N = 512;
  if (z == 0)      { src = Wq; dst = wqT;              K = 512; }
  else if (z == 1) { src = Wk; dst = wkvT;             K = 768; }
  else if (z == 2) { src = Wv; dst = wkvT + 512 * 768; K = 768; }
  else             { src = Wo; dst = woT;              K = 512; }
  int k0 = kx * 64, n0 = ny * 64;
  if (k0 >= K) return;
  __shared__ u16 t[64][65];
  int tid = threadIdx.x, jr = tid & 63, ir = tid >> 6;
  for (int it = 0; it < 16; ++it) { int i = it * 4 + ir; t[i][jr] = f2bf(src[(size_t)(k0 + i) * N + n0 + jr]); }
  __syncthreads();
  for (int it = 0; it < 16; ++it) { int i = it * 4 + ir; dst[(size_t)(n0 + i) * K + k0 + jr] = t[jr][i]; }
}

// ---------------- shared GEMM body: 128x256 dual-N tile, BK=32 ----------------
// R5: each block stages ONE A panel + TWO 128-col B tiles per K-step (arithmetic
// intensity x2: A traffic halves, 32 MFMA per barrier-period). R4 showed the
// structure is operand-traffic bound (FETCH fix + counted vmcnt = no dur change),
// so the lever is per-FLOP traffic, not wait placement.
// 3-buffer LDS pipeline, prefetch depth 2, counted vmcnt + raw s_barrier.
// Steady wait: vmcnt(8) F32A (4 ALD + 4 B-g2l in flight) / vmcnt(6) bf16; tail 0.
// XOR-chunk swizzle unchanged (R2/R4-verified conflict-free).
// Al: [3][128][32] (24KB). Bl: [3][2][128][32] (48KB).
template <int MODE, bool F32A>
__device__ __forceinline__ void gemm_body(const void* __restrict__ Av, const u16* __restrict__ Bt,
                                          void* __restrict__ C0, void* __restrict__ C1,
                                          const float* __restrict__ bias, int N, int K,
                                          float oscale, int nbx, int mby,
                                          u16* Al, u16* Bl) {
  int mb = mby * 128, nb = nbx * 256;
  int tid = threadIdx.x, lane = tid & 63, quad = lane >> 4, l16 = lane & 15, wave = tid >> 6;
  int wm = (wave >> 1) * 64, wn = (wave & 1) * 64;
  f4v acc[2][4][4];
  #pragma unroll
  for (int ct = 0; ct < 2; ct++)
    #pragma unroll
    for (int i = 0; i < 4; i++)
      #pragma unroll
      for (int j = 0; j < 4; j++) acc[ct][i][j] = (f4v){0.f, 0.f, 0.f, 0.f};

  int r0 = tid >> 2;
  int cs = ((tid & 3) ^ ((r0 >> 1) & 3)) * 8;     // swizzled source chunk -> element offset
  int lin = tid * 8;                               // linear LDS dest (elements)
  const u16* Bp0 = Bt + (size_t)(nb + r0) * K + cs;   // tile0 rows 0-63
  const u16* Bp1 = Bp0 + (size_t)64 * K;              // tile0 rows 64-127
  const u16* Bp2 = Bp0 + (size_t)128 * K;             // tile1 rows 0-63
  const u16* Bp3 = Bp0 + (size_t)192 * K;             // tile1 rows 64-127
  const float* Af0 = nullptr; const float* Af1 = nullptr;
  const u16* Ap0 = nullptr; const u16* Ap1 = nullptr;
  if constexpr (F32A) {
    Af0 = (const float*)Av + (size_t)(mb + r0) * K + cs;
    Af1 = Af0 + (size_t)64 * K;
  } else {
    Ap0 = (const u16*)Av + (size_t)(mb + r0) * K + cs;
    Ap1 = Ap0 + (size_t)64 * K;
  }
  float4 ra[4], rb[4];                             // 2 in-flight fp32 A reg sets (literal idx only)

#define BSTG(k0, bl_) do { \
    g2l16(Bp0 + (k0), (bl_) + lin);        g2l16(Bp1 + (k0), (bl_) + lin + 2048); \
    g2l16(Bp2 + (k0), (bl_) + lin + 4096); g2l16(Bp3 + (k0), (bl_) + lin + 6144); } while (0)
#define ASTG(k0, al_) do { g2l16(Ap0 + (k0), (al_) + lin); g2l16(Ap1 + (k0), (al_) + lin + 2048); } while (0)
#define ALD(k0, s) do { \
    s[0] = *(const float4*)(Af0 + (k0)); s[1] = *(const float4*)(Af0 + (k0) + 4); \
    s[2] = *(const float4*)(Af1 + (k0)); s[3] = *(const float4*)(Af1 + (k0) + 4); } while (0)
#define AWR(s, al_) do { union { u32 d[4]; s8v v; } ua, ub; \
    ua.d[0] = cvtpk(s[0].x, s[0].y); ua.d[1] = cvtpk(s[0].z, s[0].w); \
    ua.d[2] = cvtpk(s[1].x, s[1].y); ua.d[3] = cvtpk(s[1].z, s[1].w); \
    ub.d[0] = cvtpk(s[2].x, s[2].y); ub.d[1] = cvtpk(s[2].z, s[2].w); \
    ub.d[2] = cvtpk(s[3].x, s[3].y); ub.d[3] = cvtpk(s[3].z, s[3].w); \
    *(s8v*)((al_) + lin) = ua.v; *(s8v*)((al_) + lin + 2048) = ub.v; } while (0)

  u16 *Ar = Al, *Aw = Al + 4096, *As = Al + 8192;
  u16 *Br = Bl, *Bw = Bl + 8192, *Bs = Bl + 16384;
  if constexpr (F32A) {
    ALD(0, ra); BSTG(0, Br); AWR(ra, Ar);          // tile 0: A via regs->LDS (implicit vmcnt wait)
    ALD(32, rb); BSTG(32, Bw);                     // tile 1 in flight
  } else {
    ASTG(0, Ar); BSTG(0, Br);
    ASTG(32, Aw); BSTG(32, Bw);
  }

  int nk = K >> 5;
  int swq8 = (quad ^ ((l16 >> 1) & 3)) * 8;        // read-side chunk, loop-invariant
  for (int t = 0; t < nk; ++t) {
    // counted drain: only tile t's staging must complete; tile t+1 stays in flight.
    if (t + 1 < nk) {
      if constexpr (F32A) asm volatile("s_waitcnt vmcnt(8) lgkmcnt(0)" ::: "memory");
      else                asm volatile("s_waitcnt vmcnt(6) lgkmcnt(0)" ::: "memory");
    } else {
      asm volatile("s_waitcnt vmcnt(0) lgkmcnt(0)" ::: "memory");
    }
    __builtin_amdgcn_s_barrier();
    asm volatile("" ::: "memory");                 // no loads hoist above the barrier
    __builtin_amdgcn_sched_barrier(0);

    if (t + 2 < nk) {
      int nxt = (t + 2) * 32;
      if constexpr (F32A) {
        if (t & 1) { ALD(nxt, rb); } else { ALD(nxt, ra); }   // set (t+2)&1
        BSTG(nxt, Bs);
      } else {
        ASTG(nxt, As); BSTG(nxt, Bs);
      }
    }

    s8v af[4], bfr[2][4];
    #pragma unroll
    for (int i = 0; i < 4; i++) af[i] = *(const s8v*)(Ar + (wm + i * 16 + l16) * 32 + swq8);
    #pragma unroll
    for (int ct = 0; ct < 2; ct++)
      #pragma unroll
      for (int j = 0; j < 4; j++)
        bfr[ct][j] = *(const s8v*)(Br + ct * 4096 + (wn + j * 16 + l16) * 32 + swq8);
    #pragma unroll
    for (int ct = 0; ct < 2; ct++)
      #pragma unroll
      for (int i = 0; i < 4; i++)
        #pragma unroll
        for (int j = 0; j < 4; j++)
          acc[ct][i][j] = __builtin_amdgcn_mfma_f32_16x16x32_bf16(af[i], bfr[ct][j], acc[ct][i][j], 0, 0, 0);

    if constexpr (F32A) {
      if (t + 1 < nk) {                            // write tile t+1's A after the MFMA cluster
        if (t & 1) { AWR(ra, Aw); } else { AWR(rb, Aw); }     // set (t+1)&1
      }
    }
    u16* tA = Ar; Ar = Aw; Aw = As; As = tA;       // rotate read/write/stage buffers
    u16* tB = Br; Br = Bw; Bw = Bs; Bs = tB;
  }
#undef BSTG
#undef ASTG
#undef ALD
#undef AWR
  #pragma unroll
  for (int ct = 0; ct < 2; ct++) {
    #pragma unroll
    for (int i = 0; i < 4; i++) {
      int rbase = mb + wm + i * 16 + quad * 4;
      #pragma unroll
      for (int j = 0; j < 4; j++) {
        int col = nb + ct * 128 + wn + j * 16 + l16;
        if (MODE == 0) {
          u16* Cb = (u16*)C0;
          #pragma unroll
          for (int r = 0; r < 4; r++) Cb[(size_t)(rbase + r) * N + col] = f2bf(acc[ct][i][j][r] * oscale);
        } else if (MODE == 1) {
          float* Cf = (float*)C0;
          #pragma unroll
          for (int r = 0; r < 4; r++) Cf[(size_t)(rbase + r) * N + col] = acc[ct][i][j][r] + bias[col];
        } else {
          if (col < 512) {                  // K projection -> Kb [b*NC+t][512]
            u16* Kb = (u16*)C0;
            #pragma unroll
            for (int r = 0; r < 4; r++) Kb[(size_t)(rbase + r) * 512 + col] = f2bf(acc[ct][i][j][r]);
          } else {                          // V projection -> Vt, transposed + key-permuted
            u16* Vt = (u16*)C1;
            int hd = col - 512, h = hd >> 6, d = hd & 63;
            int bb = rbase >> 10, tl = rbase & 1023;
            int tbase = tl & ~63, a0 = tl & 63;          // a0 = quad*4-aligned key-local idx
            int pb = (a0 & 32) + ((a0 & 15) >> 2) * 8 + (((a0 >> 4) & 1) << 2);
            uint2 ov;
            ov.x = pack2(acc[ct][i][j][0], acc[ct][i][j][1]);
            ov.y = pack2(acc[ct][i][j][2], acc[ct][i][j][3]);
            *(uint2*)(Vt + ((size_t)(bb * NH + h) * DH + d) * NC + tbase + pb) = ov;
          }
        }
      }
    }
  }
}

// ---------------- fused QKV projection, fp32 A direct, XCD-chunked swizzle ----------------
// 384 blocks (2/CU capacity): per XCD 16 KV (24 K-steps, first) + 32 Q. Col-tiles of the
// same A-panel are adjacent in XCD order so both readers run concurrently on one XCD's L2.
__global__ __launch_bounds__(256, 2) void proj_all(const float* __restrict__ x, const float* __restrict__ ctx,
                                                   const u16* __restrict__ wqT, const u16* __restrict__ wkvT,
                                                   u16* __restrict__ Qb, u16* __restrict__ Kb,
                                                   u16* __restrict__ Vtb, float qscale) {
  __shared__ alignas(16) u16 Al[3][128][32];
  __shared__ alignas(16) u16 Bl[3][2][128][32];
  int bx = blockIdx.x;
  int xcd = bx & 7, off = bx >> 3;        // off in [0,48)
  if (off < 16) {  // KV: M=4096, N=1024, K=768; 128 blocks, 4 col-tiles of 256 per A-panel
    int bi = xcd * 16 + off;              // [0,128)
    gemm_body<2, true>(ctx, wkvT, Kb, Vtb, nullptr, 1024, 768, 1.0f, bi & 3, bi >> 2,
                       (u16*)Al, (u16*)Bl);
  } else {         // Q: M=16384, N=512, K=512; 256 blocks, 2 col-tiles per A-panel
    int bi = xcd * 32 + (off - 16);       // [0,256)
    gemm_body<0, true>(x, wqT, Qb, nullptr, nullptr, 512, 512, qscale, bi & 1, bi >> 1,
                       (u16*)Al, (u16*)Bl);
  }
}

// ---------------- output projection (fp32 out + bias), XCD-chunked swizzle ----------------
__global__ __launch_bounds__(256, 2) void outproj(const u16* __restrict__ Ob, const u16* __restrict__ woT,
                                                  float* __restrict__ out, const float* __restrict__ bo) {
  __shared__ alignas(16) u16 Al[3][128][32];
  __shared__ alignas(16) u16 Bl[3][2][128][32];
  int bx = blockIdx.x;
  int idx = (bx & 7) * 32 + (bx >> 3);    // [0,256)
  gemm_body<1, false>(Ob, woT, out, nullptr, bo, 512, 512, 1.0f, idx & 1, idx >> 1,
                      (u16*)Al, (u16*)Bl);
}

// ---------------- flash cross-attention: 32 q/wave, 64-key tiles, 4 blocks/CU ----------------
// (unchanged from R1: MFMA-ones denominator, cvt_pk packs, pipelined chunks + setprio)
__global__ __launch_bounds__(256, 4) void attn(const u16* __restrict__ Q, const u16* __restrict__ Kb,
                                               const u16* __restrict__ Vt, u16* __restrict__ O) {
  __shared__ alignas(16) u16 Kl[2][64][64];   // 16 KB
  __shared__ alignas(16) u16 Vl[2][64][64];   // 16 KB
  int qt = blockIdx.x, h = blockIdx.y, b = blockIdx.z;
  int tid = threadIdx.x, wave = tid >> 6, lane = tid & 63, quad = lane >> 4, l16 = lane & 15;
  int q0 = qt * 128 + wave * 32;
  int x7 = l16 & 7;

  int kr = tid >> 3, kc = (tid & 7) ^ (kr & 7);
  const u16* kg = Kb + ((size_t)b * NC + kr) * 512 + h * DH + kc * 8;
  const u16* vg = Vt + ((size_t)(b * NH + h) * DH + kr) * NC + kc * 8;

#define ASTAGE(kt, buf) do { \
    const u16* kg_ = kg + (size_t)(kt) * 64 * 512; \
    const u16* vg_ = vg + (kt) * 64; \
    u16* kl_ = (u16*)Kl + (buf) * 4096; u16* vl_ = (u16*)Vl + (buf) * 4096; \
    g2l16(kg_,            kl_ + tid * 8); \
    g2l16(kg_ + 32 * 512, kl_ + (tid + 256) * 8); \
    g2l16(vg_,            vl_ + tid * 8); \
    g2l16(vg_ + 32 * NC,  vl_ + (tid + 256) * 8); } while (0)

  s8v aq[2][2];
  {
    const u16* Qp = Q + ((size_t)b * NQ + q0 + l16) * DI + h * DH + quad * 8;
    #pragma unroll
    for (int n = 0; n < 2; n++) {
      aq[n][0] = *(const s8v*)(Qp + (size_t)n * 16 * DI);
      aq[n][1] = *(const s8v*)(Qp + (size_t)n * 16 * DI + 32);
    }
  }
  s8v vones;
  #pragma unroll
  for (int i = 0; i < 8; i++) vones[i] = (short)0x3F80;

  f4v oacc[4][2];
  f4v lacc[2];
  #pragma unroll
  for (int d = 0; d < 4; d++)
    #pragma unroll
    for (int n = 0; n < 2; n++) oacc[d][n] = (f4v){0.f, 0.f, 0.f, 0.f};
  #pragma unroll
  for (int n = 0; n < 2; n++) lacc[n] = (f4v){0.f, 0.f, 0.f, 0.f};

  ASTAGE(0, 0);
  for (int kt = 0; kt < NC / 64; ++kt) {
    int buf = kt & 1;
    __syncthreads();
    if (kt + 1 < NC / 64) ASTAGE(kt + 1, buf ^ 1);
    const u16* kb = (const u16*)Kl + buf * 4096;
    const u16* vb = (const u16*)Vl + buf * 4096;

    f4v S0[2][2], S1[2][2];
    #pragma unroll
    for (int mi = 0; mi < 2; mi++)
      #pragma unroll
      for (int n = 0; n < 2; n++) { S0[mi][n] = (f4v){0.f,0.f,0.f,0.f}; S1[mi][n] = (f4v){0.f,0.f,0.f,0.f}; }
    __builtin_amdgcn_s_setprio(1);
    #pragma unroll
    for (int cd = 0; cd < 2; cd++) {
      int ch = ((4 * cd + quad) ^ x7) * 8;
      s8v k00 = *(const s8v*)(kb + (l16     ) * 64 + ch);
      s8v k01 = *(const s8v*)(kb + (l16 + 16) * 64 + ch);
      #pragma unroll
      for (int n = 0; n < 2; n++) {
        S0[0][n] = __builtin_amdgcn_mfma_f32_16x16x32_bf16(k00, aq[n][cd], S0[0][n], 0, 0, 0);
        S0[1][n] = __builtin_amdgcn_mfma_f32_16x16x32_bf16(k01, aq[n][cd], S0[1][n], 0, 0, 0);
      }
      s8v k10 = *(const s8v*)(kb + (l16 + 32) * 64 + ch);
      s8v k11 = *(const s8v*)(kb + (l16 + 48) * 64 + ch);
      #pragma unroll
      for (int n = 0; n < 2; n++) {
        S1[0][n] = __builtin_amdgcn_mfma_f32_16x16x32_bf16(k10, aq[n][cd], S1[0][n], 0, 0, 0);
        S1[1][n] = __builtin_amdgcn_mfma_f32_16x16x32_bf16(k11, aq[n][cd], S1[1][n], 0, 0, 0);
      }
    }
    __builtin_amdgcn_s_setprio(0);

    s8v pf0[2];
    #pragma unroll
    for (int n = 0; n < 2; n++) {
      float p00 = EXP2(S0[0][n][0]), p01 = EXP2(S0[0][n][1]), p02 = EXP2(S0[0][n][2]), p03 = EXP2(S0[0][n][3]);
      float p10 = EXP2(S0[1][n][0]), p11 = EXP2(S0[1][n][1]), p12 = EXP2(S0[1][n][2]), p13 = EXP2(S0[1][n][3]);
      union { u32 d[4]; s8v v; } u;
      u.d[0] = cvtpk(p00, p01); u.d[1] = cvtpk(p02, p03);
      u.d[2] = cvtpk(p10, p11); u.d[3] = cvtpk(p12, p13);
      pf0[n] = u.v;
    }
    __builtin_amdgcn_s_setprio(1);
    #pragma unroll
    for (int n = 0; n < 2; n++)
      lacc[n] = __builtin_amdgcn_mfma_f32_16x16x32_bf16(vones, pf0[n], lacc[n], 0, 0, 0);
    #pragma unroll
    for (int d = 0; d < 4; d++) {
      int ch = (quad ^ x7) * 8;
      s8v vf = *(const s8v*)(vb + (d * 16 + l16) * 64 + ch);
      #pragma unroll
      for (int n = 0; n < 2; n++)
        oacc[d][n] = __builtin_amdgcn_mfma_f32_16x16x32_bf16(vf, pf0[n], oacc[d][n], 0, 0, 0);
    }
    __builtin_amdgcn_s_setprio(0);

    s8v pf1[2];
    #pragma unroll
    for (int n = 0; n < 2; n++) {
      float p00 = EXP2(S1[0][n][0]), p01 = EXP2(S1[0][n][1]), p02 = EXP2(S1[0][n][2]), p03 = EXP2(S1[0][n][3]);
      float p10 = EXP2(S1[1][n][0]), p11 = EXP2(S1[1][n][1]), p12 = EXP2(S1[1][n][2]), p13 = EXP2(S1[1][n][3]);
      union { u32 d[4]; s8v v; } u;
      u.d[0] = cvtpk(p00, p01); u.d[1] = cvtpk(p02, p03);
      u.d[2] = cvtpk(p10, p11); u.d[3] = cvtpk(p12, p13);
      pf1[n] = u.v;
    }
    __builtin_amdgcn_s_setprio(1);
    #pragma unroll
    for (int n = 0; n < 2; n++)
      lacc[n] = __builtin_amdgcn_mfma_f32_16x16x32_bf16(vones, pf1[n], lacc[n], 0, 0, 0);
    #pragma unroll
    for (int d = 0; d < 4; d++) {
      int ch = ((4 + quad) ^ x7) * 8;
      s8v vf = *(const s8v*)(vb + (d * 16 + l16) * 64 + ch);
      #pragma unroll
      for (int n = 0; n < 2; n++)
        oacc[d][n] = __builtin_amdgcn_mfma_f32_16x16x32_bf16(vf, pf1[n], oacc[d][n], 0, 0, 0);
    }
    __builtin_amdgcn_s_setprio(0);
  }
#undef ASTAGE

  float inv[2];
  #pragma unroll
  for (int n = 0; n < 2; n++) inv[n] = 1.0f / lacc[n][0];

  #pragma unroll
  for (int d = 0; d < 4; d++)
    #pragma unroll
    for (int n = 0; n < 2; n++) {
      int q = q0 + n * 16 + l16;
      uint2 ov;
      ov.x = cvtpk(oacc[d][n][0] * inv[n], oacc[d][n][1] * inv[n]);
      ov.y = cvtpk(oacc[d][n][2] * inv[n], oacc[d][n][3] * inv[n]);
      *(uint2*)(O + ((size_t)b * NQ + q) * DI + h * DH + d * 16 + quad * 4) = ov;
    }
}

extern "C" void kernel_launch(void* const* d_in, const int* in_sizes, int n_in,
                              void* d_out, int out_size, void* d_ws, size_t ws_size,
                              hipStream_t stream) {
  const float* x   = (const float*)d_in[0];
  const float* ctx = (const float*)d_in[1];
  const float* Wq  = (const float*)d_in[2];
  const float* Wk  = (const float*)d_in[3];
  const float* Wv  = (const float*)d_in[4];
  const float* Wo  = (const float*)d_in[5];
  const float* bo  = (const float*)d_in[6];
  float* out = (float*)d_out;

  u16* w    = (u16*)d_ws;                // workspace layout (bf16 elems)
  u16* wqT  = w;                         // 262144
  u16* wkvT = wqT  + 262144;             // 786432 (Wk^T rows 0-511, Wv^T rows 512-1023)
  u16* woT  = wkvT + 786432;             // 262144
  u16* Qb   = woT  + 262144;             // 8388608 (pre-scaled by 0.125*log2e)
  u16* Kbuf = Qb   + 8388608;            // 2097152 ([b*1024+t][512])
  u16* Vtb  = Kbuf + 2097152;            // 2097152 (key-permuted V^T)
  u16* Ob   = Vtb  + 2097152;            // 8388608

  const float qscale = 0.125f * 1.44269504f;  // softmax scale + log2(e) folded into Q

  prep<<<384, 256, 0, stream>>>(Wq, Wk, Wv, Wo, wqT, wkvT, woT);
  proj_all<<<384, 256, 0, stream>>>(x, ctx, wqT, wkvT, Qb, Kbuf, Vtb, qscale);
  attn<<<dim3(32, 8, 4), 256, 0, stream>>>(Qb, Kbuf, Vtb, Ob);
  outproj<<<256, 256, 0, stream>>>(Ob, woT, out, bo);
}